// Round 4
// baseline (576.814 us; speedup 1.0000x reference)
//
#include <hip/hip_runtime.h>
#include <hip/hip_fp16.h>
#include <hip/hip_cooperative_groups.h>

namespace cg = cooperative_groups;

#define NN   50000
#define EE   800000
#define KDIN 128
#define NH   4
#define ND   16
#define NEG_SLOPE 0.2f

__device__ __forceinline__ float lrelu(float x) {
    return x > 0.f ? x : NEG_SLOPE * x;
}
__device__ __forceinline__ float h2f(unsigned short u) {
    return __half2float(__ushort_as_half(u));
}

// ---- K1: feat = h @ W  (N x 128 @ 128 x 64) -> fp16 feat + f32 el/er ----
// Also zeroes out[] and denom[] (its 800k threads == N*ND exactly), replacing
// the two hipMemsetAsync dispatches (~15-20us of per-dispatch gap each).
__global__ __launch_bounds__(256) void k_proj(
    const float* __restrict__ h, const float* __restrict__ W,
    const float* __restrict__ attn_l, const float* __restrict__ attn_r,
    unsigned short* __restrict__ feat_h, float* __restrict__ el, float* __restrict__ er,
    float* __restrict__ denom, float* __restrict__ out)
{
    __shared__ float4 Wl[KDIN * 16];   // [k][c4] : 32 KB, whole W
    __shared__ float  hrow[16 * 132];  // 16 rows padded to 132 (bank-conflict-free)

    const int tid  = threadIdx.x;
    const int gtid = blockIdx.x * 256 + tid;   // 0 .. NN*ND-1 exactly
    out[gtid] = 0.f;
    if (gtid < NN * NH) denom[gtid] = 0.f;

    const float4* W4 = (const float4*)W;
    #pragma unroll
    for (int i = 0; i < 8; ++i) Wl[tid + 256 * i] = W4[tid + 256 * i];

    const int wave = tid >> 6;
    const int lane = tid & 63;
    const int r16  = lane >> 4;   // which of the wave's 4 rows
    const int c4   = lane & 15;   // float4 column index
    const int row_base = blockIdx.x * 16 + wave * 4;

    {
        const float4* h4 = (const float4*)h;
        float4 v0 = h4[(size_t)row_base * 32 + lane];
        float4 v1 = h4[(size_t)row_base * 32 + lane + 64];
        const int i1 = lane + 64;
        *(float4*)&hrow[(wave * 4 + (lane >> 5)) * 132 + (lane & 31) * 4] = v0;
        *(float4*)&hrow[(wave * 4 + (i1  >> 5)) * 132 + (i1  & 31) * 4] = v1;
    }
    __syncthreads();

    const float* myrow = &hrow[(wave * 4 + r16) * 132];
    float4 acc = make_float4(0.f, 0.f, 0.f, 0.f);
    #pragma unroll 8
    for (int k = 0; k < KDIN; ++k) {
        float  hv = myrow[k];
        float4 w  = Wl[k * 16 + c4];
        acc.x = fmaf(hv, w.x, acc.x);
        acc.y = fmaf(hv, w.y, acc.y);
        acc.z = fmaf(hv, w.z, acc.z);
        acc.w = fmaf(hv, w.w, acc.w);
    }
    const int row = row_base + r16;

    ushort4 hv4;
    hv4.x = __half_as_ushort(__float2half_rn(acc.x));
    hv4.y = __half_as_ushort(__float2half_rn(acc.y));
    hv4.z = __half_as_ushort(__float2half_rn(acc.z));
    hv4.w = __half_as_ushort(__float2half_rn(acc.w));
    ((ushort4*)feat_h)[(size_t)row * 16 + c4] = hv4;

    const float4 al = ((const float4*)attn_l)[c4];
    const float4 ar = ((const float4*)attn_r)[c4];
    float pl = acc.x*al.x + acc.y*al.y + acc.z*al.z + acc.w*al.w;
    float pr = acc.x*ar.x + acc.y*ar.y + acc.z*ar.z + acc.w*ar.w;
    pl += __shfl_xor(pl, 1); pl += __shfl_xor(pl, 2);
    pr += __shfl_xor(pr, 1); pr += __shfl_xor(pr, 2);
    if ((c4 & 3) == 0) {
        const int head = c4 >> 2;
        el[row * NH + head] = pl;
        er[row * NH + head] = pr;
    }
}

// ---- K2 (cooperative): edge softmax-denoms, grid sync, aggregation ----
// phase 1: one thread per (edge, head): ex = exp(lrelu(el[s]+er[t])),
//          stored fp16 (reused in phase 2; R2/R3 A/B showed recompute costs
//          ~5us more than the ~7MB of extra traffic), atomicAdd into denom
//          (4 adjacent lanes -> one 16B sector).
// phase 2: one thread per (edge, d): head-sum in registers, one atomicAdd per
//          (edge,d); 16 adjacent lanes -> one 64B line of out.
// No max-subtraction (logits O(1) by construction; validated R2/R3).
__global__ __launch_bounds__(256, 8) void k_coop(
    const int* __restrict__ src, const int* __restrict__ dst,
    const float* __restrict__ el, const float* __restrict__ er,
    unsigned short* __restrict__ exh, float* __restrict__ denom,
    const unsigned short* __restrict__ feat_h, float* __restrict__ out)
{
    cg::grid_group grid = cg::this_grid();
    const int nthreads = (int)(gridDim.x * 256);
    const int tid0 = blockIdx.x * 256 + threadIdx.x;

    // phase 1: E*NH work items
    for (int i = tid0; i < EE * NH; i += nthreads) {
        const int e  = i >> 2;
        const int hd = i & 3;
        const int s = src[e], t = dst[e];
        const float x  = lrelu(el[s * NH + hd] + er[t * NH + hd]);
        const float ex = __expf(x);
        exh[i] = __half_as_ushort(__float2half_rn(ex));
        atomicAdd(&denom[t * NH + hd], ex);
    }

    __threadfence();
    grid.sync();

    // phase 2: E*ND work items
    for (int idx = tid0; idx < EE * ND; idx += nthreads) {
        const int e = idx >> 4;
        const int d = idx & 15;
        const int s = src[e], t = dst[e];
        const ushort4 exv = ((const ushort4*)exh)[e];
        const float4  dn  = ((const float4*)denom)[t];
        const float w0 = h2f(exv.x) * __builtin_amdgcn_rcpf(dn.x);
        const float w1 = h2f(exv.y) * __builtin_amdgcn_rcpf(dn.y);
        const float w2 = h2f(exv.z) * __builtin_amdgcn_rcpf(dn.z);
        const float w3 = h2f(exv.w) * __builtin_amdgcn_rcpf(dn.w);
        const unsigned short* f = feat_h + (size_t)s * (NH * ND) + d;
        float acc = w0 * h2f(f[0])
                  + w1 * h2f(f[ND])
                  + w2 * h2f(f[2 * ND])
                  + w3 * h2f(f[3 * ND]);
        atomicAdd(&out[t * ND + d], acc * 0.25f);
    }
}

extern "C" void kernel_launch(void* const* d_in, const int* in_sizes, int n_in,
                              void* d_out, int out_size, void* d_ws, size_t ws_size,
                              hipStream_t stream)
{
    const float* h  = (const float*)d_in[0];
    const float* W  = (const float*)d_in[1];
    const float* al = (const float*)d_in[2];
    const float* ar = (const float*)d_in[3];
    const int* src  = (const int*)d_in[4];
    const int* dst  = (const int*)d_in[5];
    float* out = (float*)d_out;

    // workspace layout (all 16B aligned)
    unsigned short* feat_h = (unsigned short*)d_ws;          // N*64 fp16 (6.4 MB)
    float* el    = (float*)(feat_h + (size_t)NN * 64);       // N*4 f32
    float* er    = el + (size_t)NN * NH;                     // N*4 f32
    float* denom = er + (size_t)NN * NH;                     // N*4 f32
    unsigned short* exh = (unsigned short*)(denom + (size_t)NN * NH); // E*4 fp16 (6.4 MB)

    k_proj<<<NN / 16, 256, 0, stream>>>(h, W, al, ar, feat_h, el, er, denom, out);

    int maxB = 4;
    hipOccupancyMaxActiveBlocksPerMultiprocessor(&maxB, k_coop, 256, 0);
    int grid = maxB * 256;               // 256 CUs
    if (grid > 2048) grid = 2048;
    if (grid < 256)  grid = 256;

    const int* src_a = src; const int* dst_a = dst;
    const float* el_a = el; const float* er_a = er;
    unsigned short* exh_a = exh; float* denom_a = denom;
    const unsigned short* feat_a = feat_h; float* out_a = out;
    void* args[] = { (void*)&src_a, (void*)&dst_a, (void*)&el_a, (void*)&er_a,
                     (void*)&exh_a, (void*)&denom_a, (void*)&feat_a, (void*)&out_a };
    hipLaunchCooperativeKernel((void*)k_coop, dim3(grid), dim3(256), args, 0, stream);
}

// Round 5
// 185.095 us; speedup vs baseline: 3.1163x; 3.1163x over previous
//
#include <hip/hip_runtime.h>
#include <hip/hip_fp16.h>

#define NN   50000
#define EE   800000
#define KDIN 128
#define NH   4
#define ND   16
#define NEG_SLOPE 0.2f

__device__ __forceinline__ float lrelu(float x) {
    return x > 0.f ? x : NEG_SLOPE * x;
}
__device__ __forceinline__ float h2f(unsigned short u) {
    return __half2float(__ushort_as_half(u));
}

// ---- K1: feat = h @ W  (N x 128 @ 128 x 64) -> fp16 feat + f32 el/er ----
// Also zeroes out[] and denom[] (its 800k threads == N*ND exactly), replacing
// the two hipMemsetAsync dispatches (~19us of graph-replay gap each).
__global__ __launch_bounds__(256) void k_proj(
    const float* __restrict__ h, const float* __restrict__ W,
    const float* __restrict__ attn_l, const float* __restrict__ attn_r,
    unsigned short* __restrict__ feat_h, float* __restrict__ el, float* __restrict__ er,
    float* __restrict__ denom, float* __restrict__ out)
{
    __shared__ float4 Wl[KDIN * 16];   // [k][c4] : 32 KB, whole W
    __shared__ float  hrow[16 * 132];  // 16 rows padded to 132 (bank-conflict-free)

    const int tid  = threadIdx.x;
    const int gtid = blockIdx.x * 256 + tid;   // 0 .. NN*ND-1 exactly
    out[gtid] = 0.f;
    if (gtid < NN * NH) denom[gtid] = 0.f;

    const float4* W4 = (const float4*)W;
    #pragma unroll
    for (int i = 0; i < 8; ++i) Wl[tid + 256 * i] = W4[tid + 256 * i];

    const int wave = tid >> 6;
    const int lane = tid & 63;
    const int r16  = lane >> 4;   // which of the wave's 4 rows
    const int c4   = lane & 15;   // float4 column index
    const int row_base = blockIdx.x * 16 + wave * 4;

    {
        const float4* h4 = (const float4*)h;
        float4 v0 = h4[(size_t)row_base * 32 + lane];
        float4 v1 = h4[(size_t)row_base * 32 + lane + 64];
        const int i1 = lane + 64;
        *(float4*)&hrow[(wave * 4 + (lane >> 5)) * 132 + (lane & 31) * 4] = v0;
        *(float4*)&hrow[(wave * 4 + (i1  >> 5)) * 132 + (i1  & 31) * 4] = v1;
    }
    __syncthreads();

    const float* myrow = &hrow[(wave * 4 + r16) * 132];
    float4 acc = make_float4(0.f, 0.f, 0.f, 0.f);
    #pragma unroll 8
    for (int k = 0; k < KDIN; ++k) {
        float  hv = myrow[k];
        float4 w  = Wl[k * 16 + c4];
        acc.x = fmaf(hv, w.x, acc.x);
        acc.y = fmaf(hv, w.y, acc.y);
        acc.z = fmaf(hv, w.z, acc.z);
        acc.w = fmaf(hv, w.w, acc.w);
    }
    const int row = row_base + r16;

    ushort4 hv4;
    hv4.x = __half_as_ushort(__float2half_rn(acc.x));
    hv4.y = __half_as_ushort(__float2half_rn(acc.y));
    hv4.z = __half_as_ushort(__float2half_rn(acc.z));
    hv4.w = __half_as_ushort(__float2half_rn(acc.w));
    ((ushort4*)feat_h)[(size_t)row * 16 + c4] = hv4;

    const float4 al = ((const float4*)attn_l)[c4];
    const float4 ar = ((const float4*)attn_r)[c4];
    float pl = acc.x*al.x + acc.y*al.y + acc.z*al.z + acc.w*al.w;
    float pr = acc.x*ar.x + acc.y*ar.y + acc.z*ar.z + acc.w*ar.w;
    pl += __shfl_xor(pl, 1); pl += __shfl_xor(pl, 2);
    pr += __shfl_xor(pr, 1); pr += __shfl_xor(pr, 2);
    if ((c4 & 3) == 0) {
        const int head = c4 >> 2;
        el[row * NH + head] = pl;
        er[row * NH + head] = pr;
    }
}

// ---- K2: ex = exp(lrelu(el[s]+er[t])) stored fp16; denom = segment_sum ----
// One thread per (edge, head), one-shot (no grid-stride: R4 showed block
// oversubscription is the latency-hiding mechanism here). 4 adjacent lanes'
// denom atomics hit one 16B sector. No max-subtraction (logits O(1) by
// construction; validated R1-R4, absmax ~2e-3 vs 1e-2 threshold).
__global__ __launch_bounds__(256) void k_edge(
    const int* __restrict__ src, const int* __restrict__ dst,
    const float* __restrict__ el, const float* __restrict__ er,
    unsigned short* __restrict__ exh, float* __restrict__ denom)
{
    const int i = blockIdx.x * 256 + threadIdx.x;   // E*NH total
    const int edge = i >> 2;
    const int hd   = i & 3;
    const int s = src[edge], t = dst[edge];
    const float x  = lrelu(el[s * NH + hd] + er[t * NH + hd]);
    const float ex = __expf(x);
    exh[i] = __half_as_ushort(__float2half_rn(ex));
    atomicAdd(&denom[t * NH + hd], ex);
}

// ---- K3: out[t,d] += 0.25 * sum_h (ex[e,h]/denom[t,h]) * feat_h[s,h,d] ----
// One thread per (edge, d), one-shot; loads stored fp16 ex (R3 A/B: exp
// recompute cost +5us VALU vs these bytes); head-sum in registers -> one
// atomicAdd per (edge,d); 16 adjacent lanes merge into one 64B out line.
__global__ __launch_bounds__(256) void k_agg(
    const int* __restrict__ src, const int* __restrict__ dst,
    const unsigned short* __restrict__ exh, const float* __restrict__ denom,
    const unsigned short* __restrict__ feat_h, float* __restrict__ out)
{
    const int idx  = blockIdx.x * 256 + threadIdx.x;  // E*16 total
    const int edge = idx >> 4;
    const int d    = idx & 15;
    const int s = src[edge], t = dst[edge];
    const ushort4 exv = ((const ushort4*)exh)[edge];
    const float4  dn  = ((const float4*)denom)[t];
    const float w0 = h2f(exv.x) * __builtin_amdgcn_rcpf(dn.x);
    const float w1 = h2f(exv.y) * __builtin_amdgcn_rcpf(dn.y);
    const float w2 = h2f(exv.z) * __builtin_amdgcn_rcpf(dn.z);
    const float w3 = h2f(exv.w) * __builtin_amdgcn_rcpf(dn.w);
    const unsigned short* f = feat_h + (size_t)s * (NH * ND) + d;
    float acc = w0 * h2f(f[0])
              + w1 * h2f(f[ND])
              + w2 * h2f(f[2 * ND])
              + w3 * h2f(f[3 * ND]);
    atomicAdd(&out[t * ND + d], acc * 0.25f);
}

extern "C" void kernel_launch(void* const* d_in, const int* in_sizes, int n_in,
                              void* d_out, int out_size, void* d_ws, size_t ws_size,
                              hipStream_t stream)
{
    const float* h  = (const float*)d_in[0];
    const float* W  = (const float*)d_in[1];
    const float* al = (const float*)d_in[2];
    const float* ar = (const float*)d_in[3];
    const int* src  = (const int*)d_in[4];
    const int* dst  = (const int*)d_in[5];
    float* out = (float*)d_out;

    // workspace layout (all 16B aligned)
    unsigned short* feat_h = (unsigned short*)d_ws;          // N*64 fp16 (6.4 MB)
    float* el    = (float*)(feat_h + (size_t)NN * 64);       // N*4 f32
    float* er    = el + (size_t)NN * NH;                     // N*4 f32
    float* denom = er + (size_t)NN * NH;                     // N*4 f32
    unsigned short* exh = (unsigned short*)(denom + (size_t)NN * NH); // E*4 fp16 (6.4 MB)

    k_proj<<<NN / 16,       256, 0, stream>>>(h, W, al, ar, feat_h, el, er, denom, out);
    k_edge<<<EE * NH / 256, 256, 0, stream>>>(src, dst, el, er, exh, denom);
    k_agg <<<EE * ND / 256, 256, 0, stream>>>(src, dst, exh, denom, feat_h, out);
}

// Round 6
// 183.367 us; speedup vs baseline: 3.1457x; 1.0094x over previous
//
#include <hip/hip_runtime.h>
#include <hip/hip_fp16.h>

#define NN   50000
#define EE   800000
#define KDIN 128
#define NH   4
#define ND   16
#define NEG_SLOPE 0.2f

__device__ __forceinline__ float lrelu(float x) {
    return x > 0.f ? x : NEG_SLOPE * x;
}
__device__ __forceinline__ float h2f(unsigned short u) {
    return __half2float(__ushort_as_half(u));
}

// ---- K1: feat = h @ W  (N x 128 @ 128 x 64) -> fp16 feat + f32 el/er ----
// Also zeroes out[] and denom[] (its 800k threads == N*ND exactly), replacing
// the two hipMemsetAsync dispatches.
__global__ __launch_bounds__(256) void k_proj(
    const float* __restrict__ h, const float* __restrict__ W,
    const float* __restrict__ attn_l, const float* __restrict__ attn_r,
    unsigned short* __restrict__ feat_h, float* __restrict__ el, float* __restrict__ er,
    float* __restrict__ denom, float* __restrict__ out)
{
    __shared__ float4 Wl[KDIN * 16];   // [k][c4] : 32 KB, whole W
    __shared__ float  hrow[16 * 132];  // 16 rows padded to 132 (bank-conflict-free)

    const int tid  = threadIdx.x;
    const int gtid = blockIdx.x * 256 + tid;   // 0 .. NN*ND-1 exactly
    out[gtid] = 0.f;
    if (gtid < NN * NH) denom[gtid] = 0.f;

    const float4* W4 = (const float4*)W;
    #pragma unroll
    for (int i = 0; i < 8; ++i) Wl[tid + 256 * i] = W4[tid + 256 * i];

    const int wave = tid >> 6;
    const int lane = tid & 63;
    const int r16  = lane >> 4;   // which of the wave's 4 rows
    const int c4   = lane & 15;   // float4 column index
    const int row_base = blockIdx.x * 16 + wave * 4;

    {
        const float4* h4 = (const float4*)h;
        float4 v0 = h4[(size_t)row_base * 32 + lane];
        float4 v1 = h4[(size_t)row_base * 32 + lane + 64];
        const int i1 = lane + 64;
        *(float4*)&hrow[(wave * 4 + (lane >> 5)) * 132 + (lane & 31) * 4] = v0;
        *(float4*)&hrow[(wave * 4 + (i1  >> 5)) * 132 + (i1  & 31) * 4] = v1;
    }
    __syncthreads();

    const float* myrow = &hrow[(wave * 4 + r16) * 132];
    float4 acc = make_float4(0.f, 0.f, 0.f, 0.f);
    #pragma unroll 8
    for (int k = 0; k < KDIN; ++k) {
        float  hv = myrow[k];
        float4 w  = Wl[k * 16 + c4];
        acc.x = fmaf(hv, w.x, acc.x);
        acc.y = fmaf(hv, w.y, acc.y);
        acc.z = fmaf(hv, w.z, acc.z);
        acc.w = fmaf(hv, w.w, acc.w);
    }
    const int row = row_base + r16;

    ushort4 hv4;
    hv4.x = __half_as_ushort(__float2half_rn(acc.x));
    hv4.y = __half_as_ushort(__float2half_rn(acc.y));
    hv4.z = __half_as_ushort(__float2half_rn(acc.z));
    hv4.w = __half_as_ushort(__float2half_rn(acc.w));
    ((ushort4*)feat_h)[(size_t)row * 16 + c4] = hv4;

    const float4 al = ((const float4*)attn_l)[c4];
    const float4 ar = ((const float4*)attn_r)[c4];
    float pl = acc.x*al.x + acc.y*al.y + acc.z*al.z + acc.w*al.w;
    float pr = acc.x*ar.x + acc.y*ar.y + acc.z*ar.z + acc.w*ar.w;
    pl += __shfl_xor(pl, 1); pl += __shfl_xor(pl, 2);
    pr += __shfl_xor(pr, 1); pr += __shfl_xor(pr, 2);
    if ((c4 & 3) == 0) {
        const int head = c4 >> 2;
        el[row * NH + head] = pl;
        er[row * NH + head] = pr;
    }
}

// ---- K2: ex = exp(lrelu(el[s]+er[t])) stored fp16; denom = segment_sum ----
// One thread per (edge, head), one-shot. unsafeAtomicAdd -> native
// global_atomic_add_f32 (fire-and-forget, no CAS retry loop); 4 adjacent
// lanes' atomics merge into one 16B sector at the TCC.
__global__ __launch_bounds__(256) void k_edge(
    const int* __restrict__ src, const int* __restrict__ dst,
    const float* __restrict__ el, const float* __restrict__ er,
    unsigned short* __restrict__ exh, float* __restrict__ denom)
{
    const int i = blockIdx.x * 256 + threadIdx.x;   // E*NH total
    const int edge = i >> 2;
    const int hd   = i & 3;
    const int s = src[edge], t = dst[edge];
    const float x  = lrelu(el[s * NH + hd] + er[t * NH + hd]);
    const float ex = __expf(x);
    exh[i] = __half_as_ushort(__float2half_rn(ex));
    unsafeAtomicAdd(&denom[t * NH + hd], ex);
}

// ---- K3: out[t,d] += 0.25 * sum_h (ex[e,h]/denom[t,h]) * feat_h[s,h,d] ----
// One thread per (edge, d), one-shot; head-sum in registers -> one native
// fadd atomic per (edge,d); 16 adjacent lanes merge into one 64B out line.
__global__ __launch_bounds__(256) void k_agg(
    const int* __restrict__ src, const int* __restrict__ dst,
    const unsigned short* __restrict__ exh, const float* __restrict__ denom,
    const unsigned short* __restrict__ feat_h, float* __restrict__ out)
{
    const int idx  = blockIdx.x * 256 + threadIdx.x;  // E*16 total
    const int edge = idx >> 4;
    const int d    = idx & 15;
    const int s = src[edge], t = dst[edge];
    const ushort4 exv = ((const ushort4*)exh)[edge];
    const float4  dn  = ((const float4*)denom)[t];
    const float w0 = h2f(exv.x) * __builtin_amdgcn_rcpf(dn.x);
    const float w1 = h2f(exv.y) * __builtin_amdgcn_rcpf(dn.y);
    const float w2 = h2f(exv.z) * __builtin_amdgcn_rcpf(dn.z);
    const float w3 = h2f(exv.w) * __builtin_amdgcn_rcpf(dn.w);
    const unsigned short* f = feat_h + (size_t)s * (NH * ND) + d;
    float acc = w0 * h2f(f[0])
              + w1 * h2f(f[ND])
              + w2 * h2f(f[2 * ND])
              + w3 * h2f(f[3 * ND]);
    unsafeAtomicAdd(&out[t * ND + d], acc * 0.25f);
}

extern "C" void kernel_launch(void* const* d_in, const int* in_sizes, int n_in,
                              void* d_out, int out_size, void* d_ws, size_t ws_size,
                              hipStream_t stream)
{
    const float* h  = (const float*)d_in[0];
    const float* W  = (const float*)d_in[1];
    const float* al = (const float*)d_in[2];
    const float* ar = (const float*)d_in[3];
    const int* src  = (const int*)d_in[4];
    const int* dst  = (const int*)d_in[5];
    float* out = (float*)d_out;

    // workspace layout (all 16B aligned)
    unsigned short* feat_h = (unsigned short*)d_ws;          // N*64 fp16 (6.4 MB)
    float* el    = (float*)(feat_h + (size_t)NN * 64);       // N*4 f32
    float* er    = el + (size_t)NN * NH;                     // N*4 f32
    float* denom = er + (size_t)NN * NH;                     // N*4 f32
    unsigned short* exh = (unsigned short*)(denom + (size_t)NN * NH); // E*4 fp16 (6.4 MB)

    k_proj<<<NN / 16,       256, 0, stream>>>(h, W, al, ar, feat_h, el, er, denom, out);
    k_edge<<<EE * NH / 256, 256, 0, stream>>>(src, dst, el, er, exh, denom);
    k_agg <<<EE * ND / 256, 256, 0, stream>>>(src, dst, exh, denom, feat_h, out);
}